// Round 4
// baseline (426.137 us; speedup 1.0000x reference)
//
#include <hip/hip_runtime.h>
#include <math.h>

#define D 256        // d_in == d_out == 256
#define TM 32        // target rows per block (1250 blocks)
#define KC 8         // K-chunk for W staging (8KB Bs -> 40KB LDS -> 4 blocks/CU)
#define LN_EPS 1e-5f
#define SCAN_CHUNK 1024   // elements per block in scan kernels

// ---------------------------------------------------------------------------
// CSR build: histogram -> scan (2 kernels) -> reorder
// ---------------------------------------------------------------------------
__global__ __launch_bounds__(256) void hist_kernel(
    const int* __restrict__ rows, int* __restrict__ cnt, int nnz)
{
    const int e = blockIdx.x * 256 + threadIdx.x;
    if (e < nnz) atomicAdd(&cnt[rows[e]], 1);
}

__global__ __launch_bounds__(256) void scan1_kernel(
    const int* __restrict__ cnt, int* __restrict__ row_ptr,
    int* __restrict__ partials, int n)
{
    const int tid = threadIdx.x;
    const int base = blockIdx.x * SCAN_CHUNK + tid * 4;
    int v[4];
#pragma unroll
    for (int q = 0; q < 4; q++) {
        const int i = base + q;
        v[q] = (i < n) ? cnt[i] : 0;
    }
    const int tsum = v[0] + v[1] + v[2] + v[3];

    const int lane = tid & 63;
    int s = tsum;
#pragma unroll
    for (int off = 1; off < 64; off <<= 1) {
        const int t = __shfl_up(s, off);
        if (lane >= off) s += t;
    }
    __shared__ int wtot[4];
    if (lane == 63) wtot[tid >> 6] = s;
    __syncthreads();
    const int w = tid >> 6;
    int woff = 0;
#pragma unroll
    for (int u = 0; u < 4; u++) if (u < w) woff += wtot[u];

    int run = woff + s - tsum;
#pragma unroll
    for (int q = 0; q < 4; q++) {
        const int i = base + q;
        if (i < n) row_ptr[i] = run;
        run += v[q];
    }
    if (tid == 255) partials[blockIdx.x] = woff + s;
}

// Merged scan2+scan3: each block wave-scans the (<=64) partials itself,
// then applies its exclusive prefix.
__global__ __launch_bounds__(256) void scan23_kernel(
    int* __restrict__ row_ptr, int* __restrict__ cursor,
    const int* __restrict__ partials, int n, int nnz, int nb)
{
    const int tid = threadIdx.x;
    __shared__ int s_add;
    if (tid < 64) {
        const int v = (tid < nb) ? partials[tid] : 0;
        int s = v;
#pragma unroll
        for (int off = 1; off < 64; off <<= 1) {
            const int u = __shfl_up(s, off);
            if (tid >= off) s += u;
        }
        if (tid == (int)blockIdx.x) s_add = s - v;   // exclusive prefix
    }
    __syncthreads();
    const int add = s_add;

    const int base = blockIdx.x * SCAN_CHUNK + tid * 4;
#pragma unroll
    for (int q = 0; q < 4; q++) {
        const int i = base + q;
        if (i < n) {
            const int rp = row_ptr[i] + add;
            row_ptr[i] = rp;
            cursor[i]  = rp;
        }
    }
    if (blockIdx.x == 0 && tid == 0) row_ptr[n] = nnz;
}

__global__ __launch_bounds__(256) void reorder_kernel(
    const int* __restrict__ rows, const int* __restrict__ cols,
    const float* __restrict__ vals, int* __restrict__ cursor,
    int* __restrict__ scol, float* __restrict__ sval, int nnz)
{
    const int e = blockIdx.x * 256 + threadIdx.x;
    if (e < nnz) {
        const int r = rows[e];
        const int pos = atomicAdd(&cursor[r], 1);
        scol[pos] = cols[e];
        sval[pos] = vals[e];
    }
}

// ---------------------------------------------------------------------------
// FUSED gather-SpMM + GEMM + bias + LayerNorm + GELU.
//
// Round-2 post-mortem: VGPR_Count=60 -> allocator could NOT keep the 8-deep
// load batch in flight (needs >=80 regs); compiler targeted 8 waves/SIMD
// although LDS caps the kernel at 4 blocks/CU (16 waves). Also each row paid
// a dependent ~400cy metadata (scol/sval) stall before its x loads.
// This round:
//   - __launch_bounds__(256, 4): min 4 waves/EU == the LDS occupancy ->
//     VGPR budget 128, so xv[8] stays resident and 8 loads stay in flight.
//   - Wave-scope metadata hoist: load scol/sval for the wave's whole 8-row
//     edge range (avg 56 edges, <=64 in ~86% of waves; windowed reload
//     otherwise) ONCE; rows consume it via __shfl. 1 metadata stall/wave
//     instead of 8.
//   - Batches padded to 8 with clamped slot + weight 0 (pad = L1 hit).
// n_tgt = 40000 = 1250*32 exactly -> no row guards.
// ---------------------------------------------------------------------------
__global__ __launch_bounds__(256, 4) void fused_spmm_gemm_kernel(
    const float* __restrict__ x, const int* __restrict__ row_ptr,
    const int* __restrict__ scol, const float* __restrict__ sval,
    const float* __restrict__ Wm, const float* __restrict__ bias,
    const float* __restrict__ gamma, const float* __restrict__ beta,
    float* __restrict__ out)
{
    __shared__ float As[TM][D];        // 32 KB: gathered rows (fp32)
    __shared__ float Bs[KC][D];        // 8 KB: W K-chunk

    const int tid  = threadIdx.x;
    const int wv   = tid >> 6;         // wave 0..3
    const int lane = tid & 63;
    const int r0   = blockIdx.x * TM;

    // ---- Phase 1: gather 8 rows per wave ----
    const int rbase = r0 + wv * 8;
    int rp = 0;
    if (lane < 9) rp = row_ptr[rbase + lane];   // rbase+8 <= n_tgt, valid
    const int rbeg = __shfl(rp, 0);
    const int rend = __shfl(rp, 8);

    // wave-scope metadata window [wbase, wbase+64)
    int wbase = rbeg;
    int   cidx = 0;
    float cval = 0.f;
    {
        const int tot = min(64, rend - wbase);
        if (lane < tot) {
            cidx = scol[wbase + lane];
            cval = sval[wbase + lane];
        }
    }

    for (int rr = 0; rr < 8; rr++) {
        const int beg = __shfl(rp, rr);
        const int end = __shfl(rp, rr + 1);

        float4 a0 = make_float4(0.f, 0.f, 0.f, 0.f);
        float4 a1 = a0, a2 = a0, a3 = a0;

        int e = beg;
        while (e < end) {
            if (e >= wbase + 64) {          // uniform: slide metadata window
                wbase = e;
                const int tot = min(64, rend - wbase);
                cidx = (lane < tot) ? scol[wbase + lane] : 0;
                cval = (lane < tot) ? sval[wbase + lane] : 0.f;
            }
            const int avail = min(end - e, wbase + 64 - e);
            const int bcnt  = min(8, avail);

            int   cc[8];
            float vv[8];
#pragma unroll
            for (int u = 0; u < 8; u++) {
                const int sl = (u < bcnt) ? (e + u - wbase) : (e - wbase);
                cc[u] = __shfl(cidx, sl);
                const float fv = __shfl(cval, sl);
                vv[u] = (u < bcnt) ? fv : 0.f;
            }
            // issue all 8 independent 1KB row loads before any FMA
            float4 xv[8];
#pragma unroll
            for (int u = 0; u < 8; u++)
                xv[u] = *(const float4*)(x + (size_t)cc[u] * D + 4 * lane);
#pragma unroll
            for (int u = 0; u < 8; u++) {
                float4& a = (u & 3) == 0 ? a0 : (u & 3) == 1 ? a1 :
                            (u & 3) == 2 ? a2 : a3;
                a.x = fmaf(vv[u], xv[u].x, a.x);
                a.y = fmaf(vv[u], xv[u].y, a.y);
                a.z = fmaf(vv[u], xv[u].z, a.z);
                a.w = fmaf(vv[u], xv[u].w, a.w);
            }
            e += bcnt;
        }
        const float4 s = make_float4(a0.x + a1.x + a2.x + a3.x,
                                     a0.y + a1.y + a2.y + a3.y,
                                     a0.z + a1.z + a2.z + a3.z,
                                     a0.w + a1.w + a2.w + a3.w);
        *(float4*)&As[wv * 8 + rr][4 * lane] = s;
    }
    __syncthreads();

    // ---- Phase 2: GEMM from resident As ----
    const int tr = tid >> 5;   // 0..7
    const int tc = tid & 31;   // 0..31

    float acc[4][8];
#pragma unroll
    for (int i = 0; i < 4; i++)
#pragma unroll
        for (int j = 0; j < 8; j++) acc[i][j] = 0.f;

    for (int k0 = 0; k0 < D; k0 += KC) {
        // stage B: 8 x 256 = 512 float4 slots, 2 per thread
#pragma unroll
        for (int q = 0; q < 2; q++) {
            const int idx = q * 256 + tid;
            const int kk = idx >> 6;          // 0..7
            const int c4 = (idx & 63) * 4;
            *(float4*)&Bs[kk][c4] = *(const float4*)(Wm + (size_t)(k0 + kk) * D + c4);
        }
        __syncthreads();

#pragma unroll
        for (int q = 0; q < 2; q++) {        // k-quads within chunk
            float4 a4[4];
#pragma unroll
            for (int i = 0; i < 4; i++)
                a4[i] = *(const float4*)&As[tr * 4 + i][k0 + q * 4];
#pragma unroll
            for (int kk = 0; kk < 4; kk++) {
                const float4 b0 = *(const float4*)&Bs[q * 4 + kk][4 * tc];
                const float4 b1 = *(const float4*)&Bs[q * 4 + kk][128 + 4 * tc];
#pragma unroll
                for (int i = 0; i < 4; i++) {
                    const float ai = (kk == 0) ? a4[i].x :
                                     (kk == 1) ? a4[i].y :
                                     (kk == 2) ? a4[i].z : a4[i].w;
                    acc[i][0] = fmaf(ai, b0.x, acc[i][0]);
                    acc[i][1] = fmaf(ai, b0.y, acc[i][1]);
                    acc[i][2] = fmaf(ai, b0.z, acc[i][2]);
                    acc[i][3] = fmaf(ai, b0.w, acc[i][3]);
                    acc[i][4] = fmaf(ai, b1.x, acc[i][4]);
                    acc[i][5] = fmaf(ai, b1.y, acc[i][5]);
                    acc[i][6] = fmaf(ai, b1.z, acc[i][6]);
                    acc[i][7] = fmaf(ai, b1.w, acc[i][7]);
                }
            }
        }
        __syncthreads();
    }

    // ---- epilogue: bias + LayerNorm + exact GELU
    float gm[8], bt[8], bs[8];
#pragma unroll
    for (int j = 0; j < 8; j++) {
        const int c = (j < 4) ? (4 * tc + j) : (128 + 4 * tc + (j - 4));
        gm[j] = gamma[c]; bt[j] = beta[c]; bs[j] = bias[c];
    }

#pragma unroll
    for (int i = 0; i < 4; i++) {
        float s = 0.f, ss = 0.f;
#pragma unroll
        for (int j = 0; j < 8; j++) {
            const float h = acc[i][j] + bs[j];
            acc[i][j] = h;
            s += h; ss += h * h;
        }
#pragma unroll
        for (int off = 16; off > 0; off >>= 1) {
            s  += __shfl_xor(s,  off);
            ss += __shfl_xor(ss, off);
        }
        const float mean = s * (1.f / D);
        const float var  = ss * (1.f / D) - mean * mean;
        const float rstd = rsqrtf(var + LN_EPS);

        const int row = r0 + tr * 4 + i;
        float y[8];
#pragma unroll
        for (int j = 0; j < 8; j++) {
            const float v = (acc[i][j] - mean) * rstd * gm[j] + bt[j];
            y[j] = 0.5f * v * (1.f + erff(v * 0.70710678118654752f));
        }
        float* op = out + (size_t)row * D;
        *(float4*)(op + 4 * tc)       = make_float4(y[0], y[1], y[2], y[3]);
        *(float4*)(op + 128 + 4 * tc) = make_float4(y[4], y[5], y[6], y[7]);
    }
}

// ---------------------------------------------------------------------------
extern "C" void kernel_launch(void* const* d_in, const int* in_sizes, int n_in,
                              void* d_out, int out_size, void* d_ws, size_t ws_size,
                              hipStream_t stream) {
    const float* x     = (const float*)d_in[0];
    const int*   rows  = (const int*)d_in[1];
    const int*   cols  = (const int*)d_in[2];
    const float* vals  = (const float*)d_in[3];
    const float* Wm    = (const float*)d_in[4];
    const float* bias  = (const float*)d_in[5];
    const float* gamma = (const float*)d_in[6];
    const float* beta  = (const float*)d_in[7];
    float* out = (float*)d_out;

    const int nnz   = in_sizes[1];
    const int n_tgt = out_size / D;          // 40000

    // workspace layout
    int* cnt      = (int*)d_ws;                         // [n_tgt]
    int* row_ptr  = cnt + n_tgt;                        // [n_tgt+1]
    int* cursor   = row_ptr + n_tgt + 1;                // [n_tgt]
    int* partials = cursor + n_tgt;                     // [64]
    int* scol     = partials + 64;                      // [nnz]
    float* sval   = (float*)(scol + nnz);               // [nnz]

    hipMemsetAsync(cnt, 0, (size_t)n_tgt * sizeof(int), stream);

    const int eblocks = (nnz + 255) / 256;
    hist_kernel<<<eblocks, 256, 0, stream>>>(rows, cnt, nnz);

    const int sblocks = (n_tgt + SCAN_CHUNK - 1) / SCAN_CHUNK;   // 40
    scan1_kernel<<<sblocks, 256, 0, stream>>>(cnt, row_ptr, partials, n_tgt);
    scan23_kernel<<<sblocks, 256, 0, stream>>>(row_ptr, cursor, partials,
                                               n_tgt, nnz, sblocks);

    reorder_kernel<<<eblocks, 256, 0, stream>>>(rows, cols, vals, cursor,
                                                scol, sval, nnz);

    const int gblocks = n_tgt / TM;   // 1250
    fused_spmm_gemm_kernel<<<gblocks, 256, 0, stream>>>(
        x, row_ptr, scol, sval, Wm, bias, gamma, beta, out);
}

// Round 6
// 420.712 us; speedup vs baseline: 1.0129x; 1.0129x over previous
//
#include <hip/hip_runtime.h>
#include <math.h>

#define D 256        // d_in == d_out == 256
#define TM 32        // target rows per block (1250 blocks)
#define KC 8         // K-chunk for W staging (8KB Bs -> 40KB LDS -> 4 blocks/CU)
#define LN_EPS 1e-5f
#define SCAN_CHUNK 1024   // elements per block in scan kernels

// ---------------------------------------------------------------------------
// CSR build: histogram -> scan (2 kernels) -> reorder   (~8us total; not the
// lever: measured budget is ~244us harness poison-fills + fused kernel)
// ---------------------------------------------------------------------------
__global__ __launch_bounds__(256) void hist_kernel(
    const int* __restrict__ rows, int* __restrict__ cnt, int nnz)
{
    const int e = blockIdx.x * 256 + threadIdx.x;
    if (e < nnz) atomicAdd(&cnt[rows[e]], 1);
}

__global__ __launch_bounds__(256) void scan1_kernel(
    const int* __restrict__ cnt, int* __restrict__ row_ptr,
    int* __restrict__ partials, int n)
{
    const int tid = threadIdx.x;
    const int base = blockIdx.x * SCAN_CHUNK + tid * 4;
    int v[4];
#pragma unroll
    for (int q = 0; q < 4; q++) {
        const int i = base + q;
        v[q] = (i < n) ? cnt[i] : 0;
    }
    const int tsum = v[0] + v[1] + v[2] + v[3];

    const int lane = tid & 63;
    int s = tsum;
#pragma unroll
    for (int off = 1; off < 64; off <<= 1) {
        const int t = __shfl_up(s, off);
        if (lane >= off) s += t;
    }
    __shared__ int wtot[4];
    if (lane == 63) wtot[tid >> 6] = s;
    __syncthreads();
    const int w = tid >> 6;
    int woff = 0;
#pragma unroll
    for (int u = 0; u < 4; u++) if (u < w) woff += wtot[u];

    int run = woff + s - tsum;
#pragma unroll
    for (int q = 0; q < 4; q++) {
        const int i = base + q;
        if (i < n) row_ptr[i] = run;
        run += v[q];
    }
    if (tid == 255) partials[blockIdx.x] = woff + s;
}

// Merged scan2+scan3: each block wave-scans the (<=64) partials itself,
// then applies its exclusive prefix.
__global__ __launch_bounds__(256) void scan23_kernel(
    int* __restrict__ row_ptr, int* __restrict__ cursor,
    const int* __restrict__ partials, int n, int nnz, int nb)
{
    const int tid = threadIdx.x;
    __shared__ int s_add;
    if (tid < 64) {
        const int v = (tid < nb) ? partials[tid] : 0;
        int s = v;
#pragma unroll
        for (int off = 1; off < 64; off <<= 1) {
            const int u = __shfl_up(s, off);
            if (tid >= off) s += u;
        }
        if (tid == (int)blockIdx.x) s_add = s - v;   // exclusive prefix
    }
    __syncthreads();
    const int add = s_add;

    const int base = blockIdx.x * SCAN_CHUNK + tid * 4;
#pragma unroll
    for (int q = 0; q < 4; q++) {
        const int i = base + q;
        if (i < n) {
            const int rp = row_ptr[i] + add;
            row_ptr[i] = rp;
            cursor[i]  = rp;
        }
    }
    if (blockIdx.x == 0 && tid == 0) row_ptr[n] = nnz;
}

__global__ __launch_bounds__(256) void reorder_kernel(
    const int* __restrict__ rows, const int* __restrict__ cols,
    const float* __restrict__ vals, int* __restrict__ cursor,
    int* __restrict__ scol, float* __restrict__ sval, int nnz)
{
    const int e = blockIdx.x * 256 + threadIdx.x;
    if (e < nnz) {
        const int r = rows[e];
        const int pos = atomicAdd(&cursor[r], 1);
        scol[pos] = cols[e];
        sval[pos] = vals[e];
    }
}

// ---------------------------------------------------------------------------
// FUSED gather-SpMM + GEMM + bias + LayerNorm + GELU.
//
// Round-5 post-mortem: tied "+v"(float4) operands on s_waitcnt don't compile
// ("tied indirect register inputs"). Same mechanism, supported spelling
// (guide rule #18 / m214 r263 recipe):
//   - 8x global_load_dwordx4 volatile asm (mutual program order preserved),
//   - asm volatile("s_waitcnt vmcnt(0)" ::: "memory")  — stays after loads,
//   - __builtin_amdgcn_sched_barrier(0)                — FMAs can't hoist
//     above the waitcnt (hipcc would otherwise move register-only consumers
//     past an inline-asm waitcnt despite the "memory" clobber).
// Goal unchanged: force all 8 loads in flight (MLP 8, not 2) -> gather phase
// moves from latency-bound toward BW-bound. ~32 data VGPRs forced live ->
// expect VGPR ~100 (the (256,4) bound permits 128; LDS caps at 4 blocks/CU
// anyway, so no occupancy loss).
// n_tgt = 40000 = 1250*32 exactly -> no row guards.
// ---------------------------------------------------------------------------
__global__ __launch_bounds__(256, 4) void fused_spmm_gemm_kernel(
    const float* __restrict__ x, const int* __restrict__ row_ptr,
    const int* __restrict__ scol, const float* __restrict__ sval,
    const float* __restrict__ Wm, const float* __restrict__ bias,
    const float* __restrict__ gamma, const float* __restrict__ beta,
    float* __restrict__ out)
{
    __shared__ float As[TM][D];        // 32 KB: gathered rows (fp32)
    __shared__ float Bs[KC][D];        // 8 KB: W K-chunk

    const int tid  = threadIdx.x;
    const int wv   = tid >> 6;         // wave 0..3
    const int lane = tid & 63;
    const int r0   = blockIdx.x * TM;

    // ---- Phase 1: gather 8 rows per wave ----
    const int rbase = r0 + wv * 8;
    int rp = 0;
    if (lane < 9) rp = row_ptr[rbase + lane];   // rbase+8 <= n_tgt, valid
    const int rbeg = __shfl(rp, 0);
    const int rend = __shfl(rp, 8);

    // wave-scope metadata window [wbase, wbase+64)
    int wbase = rbeg;
    int   cidx = 0;
    float cval = 0.f;
    {
        const int tot = min(64, rend - wbase);
        if (lane < tot) {
            cidx = scol[wbase + lane];
            cval = sval[wbase + lane];
        }
    }

    for (int rr = 0; rr < 8; rr++) {
        const int beg = __shfl(rp, rr);
        const int end = __shfl(rp, rr + 1);

        float4 a0 = make_float4(0.f, 0.f, 0.f, 0.f);
        float4 a1 = a0, a2 = a0, a3 = a0;

        int e = beg;
        while (e < end) {
            if (e >= wbase + 64) {          // uniform: slide metadata window
                wbase = e;
                const int tot = min(64, rend - wbase);
                cidx = (lane < tot) ? scol[wbase + lane] : 0;
                cval = (lane < tot) ? sval[wbase + lane] : 0.f;
            }
            const int avail = min(end - e, wbase + 64 - e);
            const int bcnt  = min(8, avail);

            // broadcast 8 (col, val); pad slots clamp to slot e with v=0
            int   cc[8];
            float vv[8];
#pragma unroll
            for (int u = 0; u < 8; u++) {
                const int sl = (u < bcnt) ? (e + u - wbase) : (e - wbase);
                cc[u] = __shfl(cidx, sl);
                const float fv = __shfl(cval, sl);
                vv[u] = (u < bcnt) ? fv : 0.f;
            }

            // ---- asm-forced 8-deep batch: issue all, wait once, then FMA
            const float* p0 = x + (size_t)cc[0] * D + 4 * lane;
            const float* p1 = x + (size_t)cc[1] * D + 4 * lane;
            const float* p2 = x + (size_t)cc[2] * D + 4 * lane;
            const float* p3 = x + (size_t)cc[3] * D + 4 * lane;
            const float* p4 = x + (size_t)cc[4] * D + 4 * lane;
            const float* p5 = x + (size_t)cc[5] * D + 4 * lane;
            const float* p6 = x + (size_t)cc[6] * D + 4 * lane;
            const float* p7 = x + (size_t)cc[7] * D + 4 * lane;
            float4 x0, x1, x2, x3, x4, x5, x6, x7;
#define GLD(dst, ptr) \
    asm volatile("global_load_dwordx4 %0, %1, off" : "=v"(dst) : "v"(ptr))
            GLD(x0, p0); GLD(x1, p1); GLD(x2, p2); GLD(x3, p3);
            GLD(x4, p4); GLD(x5, p5); GLD(x6, p6); GLD(x7, p7);
#undef GLD
            asm volatile("s_waitcnt vmcnt(0)" ::: "memory");
            __builtin_amdgcn_sched_barrier(0);

            a0.x = fmaf(vv[0], x0.x, a0.x); a0.y = fmaf(vv[0], x0.y, a0.y);
            a0.z = fmaf(vv[0], x0.z, a0.z); a0.w = fmaf(vv[0], x0.w, a0.w);
            a1.x = fmaf(vv[1], x1.x, a1.x); a1.y = fmaf(vv[1], x1.y, a1.y);
            a1.z = fmaf(vv[1], x1.z, a1.z); a1.w = fmaf(vv[1], x1.w, a1.w);
            a2.x = fmaf(vv[2], x2.x, a2.x); a2.y = fmaf(vv[2], x2.y, a2.y);
            a2.z = fmaf(vv[2], x2.z, a2.z); a2.w = fmaf(vv[2], x2.w, a2.w);
            a3.x = fmaf(vv[3], x3.x, a3.x); a3.y = fmaf(vv[3], x3.y, a3.y);
            a3.z = fmaf(vv[3], x3.z, a3.z); a3.w = fmaf(vv[3], x3.w, a3.w);
            a0.x = fmaf(vv[4], x4.x, a0.x); a0.y = fmaf(vv[4], x4.y, a0.y);
            a0.z = fmaf(vv[4], x4.z, a0.z); a0.w = fmaf(vv[4], x4.w, a0.w);
            a1.x = fmaf(vv[5], x5.x, a1.x); a1.y = fmaf(vv[5], x5.y, a1.y);
            a1.z = fmaf(vv[5], x5.z, a1.z); a1.w = fmaf(vv[5], x5.w, a1.w);
            a2.x = fmaf(vv[6], x6.x, a2.x); a2.y = fmaf(vv[6], x6.y, a2.y);
            a2.z = fmaf(vv[6], x6.z, a2.z); a2.w = fmaf(vv[6], x6.w, a2.w);
            a3.x = fmaf(vv[7], x7.x, a3.x); a3.y = fmaf(vv[7], x7.y, a3.y);
            a3.z = fmaf(vv[7], x7.z, a3.z); a3.w = fmaf(vv[7], x7.w, a3.w);

            e += bcnt;
        }
        const float4 s = make_float4(a0.x + a1.x + a2.x + a3.x,
                                     a0.y + a1.y + a2.y + a3.y,
                                     a0.z + a1.z + a2.z + a3.z,
                                     a0.w + a1.w + a2.w + a3.w);
        *(float4*)&As[wv * 8 + rr][4 * lane] = s;
    }
    __syncthreads();

    // ---- Phase 2: GEMM from resident As ----
    const int tr = tid >> 5;   // 0..7
    const int tc = tid & 31;   // 0..31

    float acc[4][8];
#pragma unroll
    for (int i = 0; i < 4; i++)
#pragma unroll
        for (int j = 0; j < 8; j++) acc[i][j] = 0.f;

    for (int k0 = 0; k0 < D; k0 += KC) {
        // stage B: 8 x 256 = 512 float4 slots, 2 per thread
#pragma unroll
        for (int q = 0; q < 2; q++) {
            const int idx = q * 256 + tid;
            const int kk = idx >> 6;          // 0..7
            const int c4 = (idx & 63) * 4;
            *(float4*)&Bs[kk][c4] = *(const float4*)(Wm + (size_t)(k0 + kk) * D + c4);
        }
        __syncthreads();

#pragma unroll
        for (int q = 0; q < 2; q++) {        // k-quads within chunk
            float4 a4[4];
#pragma unroll
            for (int i = 0; i < 4; i++)
                a4[i] = *(const float4*)&As[tr * 4 + i][k0 + q * 4];
#pragma unroll
            for (int kk = 0; kk < 4; kk++) {
                const float4 b0 = *(const float4*)&Bs[q * 4 + kk][4 * tc];
                const float4 b1 = *(const float4*)&Bs[q * 4 + kk][128 + 4 * tc];
#pragma unroll
                for (int i = 0; i < 4; i++) {
                    const float ai = (kk == 0) ? a4[i].x :
                                     (kk == 1) ? a4[i].y :
                                     (kk == 2) ? a4[i].z : a4[i].w;
                    acc[i][0] = fmaf(ai, b0.x, acc[i][0]);
                    acc[i][1] = fmaf(ai, b0.y, acc[i][1]);
                    acc[i][2] = fmaf(ai, b0.z, acc[i][2]);
                    acc[i][3] = fmaf(ai, b0.w, acc[i][3]);
                    acc[i][4] = fmaf(ai, b1.x, acc[i][4]);
                    acc[i][5] = fmaf(ai, b1.y, acc[i][5]);
                    acc[i][6] = fmaf(ai, b1.z, acc[i][6]);
                    acc[i][7] = fmaf(ai, b1.w, acc[i][7]);
                }
            }
        }
        __syncthreads();
    }

    // ---- epilogue: bias + LayerNorm + exact GELU
    float gm[8], bt[8], bs[8];
#pragma unroll
    for (int j = 0; j < 8; j++) {
        const int c = (j < 4) ? (4 * tc + j) : (128 + 4 * tc + (j - 4));
        gm[j] = gamma[c]; bt[j] = beta[c]; bs[j] = bias[c];
    }

#pragma unroll
    for (int i = 0; i < 4; i++) {
        float s = 0.f, ss = 0.f;
#pragma unroll
        for (int j = 0; j < 8; j++) {
            const float h = acc[i][j] + bs[j];
            acc[i][j] = h;
            s += h; ss += h * h;
        }
#pragma unroll
        for (int off = 16; off > 0; off >>= 1) {
            s  += __shfl_xor(s,  off);
            ss += __shfl_xor(ss, off);
        }
        const float mean = s * (1.f / D);
        const float var  = ss * (1.f / D) - mean * mean;
        const float rstd = rsqrtf(var + LN_EPS);

        const int row = r0 + tr * 4 + i;
        float y[8];
#pragma unroll
        for (int j = 0; j < 8; j++) {
            const float v = (acc[i][j] - mean) * rstd * gm[j] + bt[j];
            y[j] = 0.5f * v * (1.f + erff(v * 0.70710678118654752f));
        }
        float* op = out + (size_t)row * D;
        *(float4*)(op + 4 * tc)       = make_float4(y[0], y[1], y[2], y[3]);
        *(float4*)(op + 128 + 4 * tc) = make_float4(y[4], y[5], y[6], y[7]);
    }
}

// ---------------------------------------------------------------------------
extern "C" void kernel_launch(void* const* d_in, const int* in_sizes, int n_in,
                              void* d_out, int out_size, void* d_ws, size_t ws_size,
                              hipStream_t stream) {
    const float* x     = (const float*)d_in[0];
    const int*   rows  = (const int*)d_in[1];
    const int*   cols  = (const int*)d_in[2];
    const float* vals  = (const float*)d_in[3];
    const float* Wm    = (const float*)d_in[4];
    const float* bias  = (const float*)d_in[5];
    const float* gamma = (const float*)d_in[6];
    const float* beta  = (const float*)d_in[7];
    float* out = (float*)d_out;

    const int nnz   = in_sizes[1];
    const int n_tgt = out_size / D;          // 40000

    // workspace layout
    int* cnt      = (int*)d_ws;                         // [n_tgt]
    int* row_ptr  = cnt + n_tgt;                        // [n_tgt+1]
    int* cursor   = row_ptr + n_tgt + 1;                // [n_tgt]
    int* partials = cursor + n_tgt;                     // [64]
    int* scol     = partials + 64;                      // [nnz]
    float* sval   = (float*)(scol + nnz);               // [nnz]

    (void)hipMemsetAsync(cnt, 0, (size_t)n_tgt * sizeof(int), stream);

    const int eblocks = (nnz + 255) / 256;
    hist_kernel<<<eblocks, 256, 0, stream>>>(rows, cnt, nnz);

    const int sblocks = (n_tgt + SCAN_CHUNK - 1) / SCAN_CHUNK;   // 40
    scan1_kernel<<<sblocks, 256, 0, stream>>>(cnt, row_ptr, partials, n_tgt);
    scan23_kernel<<<sblocks, 256, 0, stream>>>(row_ptr, cursor, partials,
                                               n_tgt, nnz, sblocks);

    reorder_kernel<<<eblocks, 256, 0, stream>>>(rows, cols, vals, cursor,
                                                scol, sval, nnz);

    const int gblocks = n_tgt / TM;   // 1250
    fused_spmm_gemm_kernel<<<gblocks, 256, 0, stream>>>(
        x, row_ptr, scol, sval, Wm, bias, gamma, beta, out);
}